// Round 1
// baseline (533.963 us; speedup 1.0000x reference)
//
#include <hip/hip_runtime.h>
#include <hip/hip_bf16.h>

#define NT   8192
#define DD   2048
#define HH   1408
#define NE   8
#define CAPT 1024

typedef __bf16 bf16x8 __attribute__((ext_vector_type(8)));
typedef float  f32x4  __attribute__((ext_vector_type(4)));
typedef unsigned short us8 __attribute__((ext_vector_type(8)));

__device__ __forceinline__ unsigned short f2bf(float f) {
  union { float f; unsigned u; } v; v.f = f;
  unsigned r = v.u + 0x7fffu + ((v.u >> 16) & 1u);
  return (unsigned short)(r >> 16);
}

__device__ __forceinline__ void load_lds16(const void* g, void* l) {
  __builtin_amdgcn_global_load_lds(
      (const __attribute__((address_space(1))) unsigned int*)g,
      (__attribute__((address_space(3))) unsigned int*)l, 16, 0, 0);
}

// fp32 -> bf16 (RNE), 8 elems/thread: 2x float4 load, 1x 16B store
__global__ __launch_bounds__(256) void cvt_bf16_kernel(
    const float* __restrict__ in, unsigned short* __restrict__ out) {
  size_t i = ((size_t)blockIdx.x * 256 + threadIdx.x) * 8;
  const float4* p = reinterpret_cast<const float4*>(in + i);
  float4 a = p[0], b = p[1];
  us8 o;
  o[0] = f2bf(a.x); o[1] = f2bf(a.y); o[2] = f2bf(a.z); o[3] = f2bf(a.w);
  o[4] = f2bf(b.x); o[5] = f2bf(b.y); o[6] = f2bf(b.z); o[7] = f2bf(b.w);
  *reinterpret_cast<us8*>(out + i) = o;
}

// Fused gate+up GEMM: h = silu(x@w1^T) * (x@w3^T), per-expert.
// Block: 256 thr (4 waves, 2x2), tile 128(M) x 64(N), BK=32, two B operands.
// Per wave per K-iter: 16 MFMA (2 gates x 4m x 2n), 8 ds_read_b128 (m97 mix).
__global__ __launch_bounds__(256) void gateup_gemm(
    const unsigned short* __restrict__ xb,   // [NT, DD] bf16
    const unsigned short* __restrict__ w1b,  // [NE, HH, DD] bf16
    const unsigned short* __restrict__ w3b,  // [NE, HH, DD] bf16
    const int* __restrict__ counts,
    unsigned short* __restrict__ h)          // [NT, HH] bf16
{
  __shared__ __align__(16) unsigned short As[128 * 32];
  __shared__ __align__(16) unsigned short B1s[64 * 32];
  __shared__ __align__(16) unsigned short B3s[64 * 32];

  const int e  = blockIdx.z;
  const int m0 = blockIdx.y * 128;
  const int n0 = blockIdx.x * 64;

  int start = 0;
  for (int i = 0; i < e; ++i) start += counts[i];

  const int tid  = threadIdx.x;
  const int lane = tid & 63;
  const int wid  = tid >> 6;
  const int lrow = lane >> 2;        // 0..15 within a 16-row chunk
  const int lcol = (lane & 3) * 8;   // 0,8,16,24 (bf16 elems; 16B granules)

  // global staging pointers (advance by 32 elems per K-iter)
  const unsigned short* ga  = xb  + (size_t)(start + m0 + wid * 32 + lrow) * DD + lcol;
  const unsigned short* gb1 = w1b + ((size_t)e * HH + n0 + wid * 16 + lrow) * DD + lcol;
  const unsigned short* gb3 = w3b + ((size_t)e * HH + n0 + wid * 16 + lrow) * DD + lcol;

  // LDS dests: wave-uniform chunk base + lane*16B (global_load_lds contract)
  unsigned short* lA0 = &As [(wid * 32) * 32      + lane * 8];
  unsigned short* lA1 = &As [(wid * 32 + 16) * 32 + lane * 8];
  unsigned short* lB1 = &B1s[(wid * 16) * 32      + lane * 8];
  unsigned short* lB3 = &B3s[(wid * 16) * 32      + lane * 8];

  const int fm  = lane & 15;
  const int fko = (lane >> 4) * 8;
  const int wm  = (wid >> 1) * 64;   // wave M offset
  const int wn  = (wid & 1) * 32;    // wave N offset

  f32x4 acc[2][4][2] = {};

  for (int k0 = 0; k0 < DD; k0 += 32) {
    load_lds16(ga,           lA0);
    load_lds16(ga + 16 * DD, lA1);
    load_lds16(gb1,          lB1);
    load_lds16(gb3,          lB3);
    ga += 32; gb1 += 32; gb3 += 32;
    __builtin_amdgcn_s_waitcnt(0x3f70);  // vmcnt(0)
    __syncthreads();

    bf16x8 af[4];
#pragma unroll
    for (int i = 0; i < 4; ++i)
      af[i] = *reinterpret_cast<const bf16x8*>(&As[(wm + i * 16 + fm) * 32 + fko]);
#pragma unroll
    for (int j = 0; j < 2; ++j) {
      bf16x8 b1 = *reinterpret_cast<const bf16x8*>(&B1s[(wn + j * 16 + fm) * 32 + fko]);
      bf16x8 b3 = *reinterpret_cast<const bf16x8*>(&B3s[(wn + j * 16 + fm) * 32 + fko]);
#pragma unroll
      for (int i = 0; i < 4; ++i) {
        acc[0][i][j] = __builtin_amdgcn_mfma_f32_16x16x32_bf16(af[i], b1, acc[0][i][j], 0, 0, 0);
        acc[1][i][j] = __builtin_amdgcn_mfma_f32_16x16x32_bf16(af[i], b3, acc[1][i][j], 0, 0, 0);
      }
    }
    __syncthreads();
  }

  // epilogue: silu(gate)*up -> bf16 h. C/D layout: col=lane&15, row=quad*4+reg
  const int r0 = (lane >> 4) * 4;
#pragma unroll
  for (int i = 0; i < 4; ++i)
#pragma unroll
    for (int j = 0; j < 2; ++j)
#pragma unroll
      for (int r = 0; r < 4; ++r) {
        int row = m0 + wm + i * 16 + r0 + r;
        int col = n0 + wn + j * 16 + fm;
        float gv = acc[0][i][j][r];
        float uv = acc[1][i][j][r];
        float sv = (gv / (1.0f + __expf(-gv))) * uv;
        h[(size_t)(start + row) * HH + col] = f2bf(sv);
      }
}

// Down GEMM: out = h @ w2^T, per-expert. m97 clone: 128x128 tile, BK=32.
__global__ __launch_bounds__(256) void down_gemm(
    const unsigned short* __restrict__ hb,   // [NT, HH] bf16
    const unsigned short* __restrict__ w2b,  // [NE, DD, HH] bf16
    const int* __restrict__ counts,
    float* __restrict__ out)                 // [NT, DD] fp32
{
  __shared__ __align__(16) unsigned short Hs[128 * 32];
  __shared__ __align__(16) unsigned short Ws[128 * 32];

  const int e  = blockIdx.z;
  const int m0 = blockIdx.y * 128;
  const int n0 = blockIdx.x * 128;

  int start = 0;
  for (int i = 0; i < e; ++i) start += counts[i];

  const int tid  = threadIdx.x;
  const int lane = tid & 63;
  const int wid  = tid >> 6;
  const int lrow = lane >> 2;
  const int lcol = (lane & 3) * 8;

  const unsigned short* ga = hb  + (size_t)(start + m0 + wid * 32 + lrow) * HH + lcol;
  const unsigned short* gb = w2b + ((size_t)e * DD + n0 + wid * 32 + lrow) * HH + lcol;

  unsigned short* lH0 = &Hs[(wid * 32) * 32      + lane * 8];
  unsigned short* lH1 = &Hs[(wid * 32 + 16) * 32 + lane * 8];
  unsigned short* lW0 = &Ws[(wid * 32) * 32      + lane * 8];
  unsigned short* lW1 = &Ws[(wid * 32 + 16) * 32 + lane * 8];

  const int fm  = lane & 15;
  const int fko = (lane >> 4) * 8;
  const int wm  = (wid >> 1) * 64;
  const int wn  = (wid & 1) * 64;

  f32x4 acc[4][4] = {};

  for (int k0 = 0; k0 < HH; k0 += 32) {
    load_lds16(ga,           lH0);
    load_lds16(ga + 16 * HH, lH1);
    load_lds16(gb,           lW0);
    load_lds16(gb + 16 * HH, lW1);
    ga += 32; gb += 32;
    __builtin_amdgcn_s_waitcnt(0x3f70);  // vmcnt(0)
    __syncthreads();

    bf16x8 af[4];
#pragma unroll
    for (int i = 0; i < 4; ++i)
      af[i] = *reinterpret_cast<const bf16x8*>(&Hs[(wm + i * 16 + fm) * 32 + fko]);
#pragma unroll
    for (int j = 0; j < 4; ++j) {
      bf16x8 bf_ = *reinterpret_cast<const bf16x8*>(&Ws[(wn + j * 16 + fm) * 32 + fko]);
#pragma unroll
      for (int i = 0; i < 4; ++i)
        acc[i][j] = __builtin_amdgcn_mfma_f32_16x16x32_bf16(af[i], bf_, acc[i][j], 0, 0, 0);
    }
    __syncthreads();
  }

  const int r0 = (lane >> 4) * 4;
#pragma unroll
  for (int i = 0; i < 4; ++i)
#pragma unroll
    for (int j = 0; j < 4; ++j)
#pragma unroll
      for (int r = 0; r < 4; ++r) {
        int row = m0 + wm + i * 16 + r0 + r;
        int col = n0 + wn + j * 16 + fm;
        out[(size_t)(start + row) * DD + col] = acc[i][j][r];
      }
}

extern "C" void kernel_launch(void* const* d_in, const int* in_sizes, int n_in,
                              void* d_out, int out_size, void* d_ws, size_t ws_size,
                              hipStream_t stream) {
  // setup_inputs order: x, num_tokens_per_expert, w1, w2, w3
  const float* x  = (const float*)d_in[0];
  const int*   cn = (const int*)d_in[1];
  const float* w1 = (const float*)d_in[2];
  const float* w2 = (const float*)d_in[3];
  const float* w3 = (const float*)d_in[4];
  float* out = (float*)d_out;

  // workspace layout (bytes):
  //   [0,            33554432)  xb   (later aliased by w2b)
  //   [33554432,     79691776)  w1b  (later aliased by w2b tail)
  //   [79691776,    125829120)  w3b
  //   [125829120,   148897792)  h
  char* ws = (char*)d_ws;
  unsigned short* xb  = (unsigned short*)(ws + 0);
  unsigned short* w1b = (unsigned short*)(ws + 33554432);
  unsigned short* w3b = (unsigned short*)(ws + 79691776);
  unsigned short* hb  = (unsigned short*)(ws + 125829120);
  unsigned short* w2b = (unsigned short*)(ws + 0);  // safe: xb/w1b dead after gateup_gemm

  cvt_bf16_kernel<<<(NT * DD) / 2048, 256, 0, stream>>>(x, xb);
  cvt_bf16_kernel<<<(NE * HH * DD) / 2048, 256, 0, stream>>>(w1, w1b);
  cvt_bf16_kernel<<<(NE * HH * DD) / 2048, 256, 0, stream>>>(w3, w3b);

  dim3 g1(HH / 64, CAPT / 128, NE);
  gateup_gemm<<<g1, 256, 0, stream>>>(xb, w1b, w3b, cn, hb);

  cvt_bf16_kernel<<<(NE * DD * HH) / 2048, 256, 0, stream>>>(w2, w2b);

  dim3 g2(DD / 128, CAPT / 128, NE);
  down_gemm<<<g2, 256, 0, stream>>>(hb, w2b, cn, out);
}